// Round 1
// 1885.707 us; speedup vs baseline: 1.3106x; 1.3106x over previous
//
#include <hip/hip_runtime.h>

// LSTM autoencoder: 4 layers (72->64), (64->32), (32->64), (64->72), B=512, T=512, fp32.
// Quad decomposition: 4 lanes per h-element. Lane q holds the k-chunks c%4==q of ALL
// FOUR gate rows (i,f,g,o) for its h. Each 16B LDS broadcast read feeds 16 FMAs
// (vs 4 before), cutting the LDS-pipe cost ~3.5x. Gate sums reduced with a DPP
// quad_perm butterfly (VALU, bit-identical across the quad -> redundant c state stays
// coherent), which removes the gates[] LDS array and the second barrier. xh is
// double-buffered so ONE lgkmcnt(0)+s_barrier per step suffices (no vmcnt drain:
// the out-store retires asynchronously across steps).

#define B_ 512
#define T_ 512

__device__ __forceinline__ float fast_sigmoid(float x) {
    return __builtin_amdgcn_rcpf(1.0f + __expf(-x));
}
__device__ __forceinline__ float fast_tanh(float x) {
    // 1 - 2/(e^{2x}+1): saturates correctly to +/-1 for large |x|, no NaN.
    return 1.0f - 2.0f * __builtin_amdgcn_rcpf(__expf(2.0f * x) + 1.0f);
}

// Butterfly sum across a quad (lanes 4k..4k+3). quad_perm[1,0,3,2]=0xB1 (xor 1),
// quad_perm[2,3,0,1]=0x4E (xor 2). Result is bit-identical on all 4 lanes.
__device__ __forceinline__ float quad_allsum(float v) {
    int t = __builtin_amdgcn_update_dpp(0, __float_as_int(v), 0xB1, 0xF, 0xF, true);
    v += __int_as_float(t);
    t = __builtin_amdgcn_update_dpp(0, __float_as_int(v), 0x4E, 0xF, 0xF, true);
    v += __int_as_float(t);
    return v;
}

template <int IN, int H>
__global__ __launch_bounds__(4 * H, 2)   // minwaves=2 -> 256-VGPR cap: weights stay in VGPRs,
                                         // no AGPR-split copy overhead (VGPR=84 pathology).
void lstm_quad_kernel(const float* __restrict__ x,    // [B, T, IN]
                      const float* __restrict__ Wih,  // [4H, IN]
                      const float* __restrict__ Whh,  // [4H, H]
                      const float* __restrict__ bih,  // [4H]
                      const float* __restrict__ bhh,  // [4H]
                      float* __restrict__ out)        // [B, T, H]
{
    constexpr int IN4 = IN / 4;
    constexpr int H4  = H / 4;
    constexpr int KW4 = IN4 + H4;          // f4 chunks of [x_t | h]
    constexpr int CH  = (KW4 + 3) / 4;     // chunks per lane (last one may be guarded)
    static_assert(IN % 4 == 0 && H % 4 == 0, "vec4 layout");

    // Double-buffered [x | h] so a single barrier per step has no WAR hazard:
    // step t reads buf[t&1], writes buf[(t+1)&1].
    __shared__ __align__(16) float4 buf[2][KW4];

    const int tid = threadIdx.x;
    const int h   = tid >> 2;   // h-element owned by this quad
    const int q   = tid & 3;    // k-slice within the quad
    const int b   = blockIdx.x;

    // ---- load this lane's weight slices: 4 gate rows, chunks c = 4j+q ----
    float4 w[4][CH];
    float  bias[4];
#pragma unroll
    for (int gi = 0; gi < 4; ++gi) {
        const int r = h + gi * H;  // PyTorch gate order: i, f, g, o
        const float4* wi = reinterpret_cast<const float4*>(Wih + r * IN);
        const float4* wh = reinterpret_cast<const float4*>(Whh + r * H);
#pragma unroll
        for (int j = 0; j < CH; ++j) {
            const int ci = 4 * j + q;
            if (ci < KW4) w[gi][j] = (ci < IN4) ? wi[ci] : wh[ci - IN4];
        }
        bias[gi] = bih[r] + bhh[r];
    }

    const float4* xg   = reinterpret_cast<const float4*>(x + (size_t)b * T_ * IN);
    float*        outb = out + (size_t)b * T_ * H;

    // ---- init buf[0] with x_0 and h=0 ----
    float4 xreg;
    if (tid < IN4) { xreg = xg[tid]; buf[0][tid] = xreg; }
    if (tid < H4)  buf[0][IN4 + tid] = make_float4(0.f, 0.f, 0.f, 0.f);
    float c_st = 0.0f;
    __syncthreads();

    for (int t = 0; t < T_; ++t) {
        const float4* __restrict__ xb = buf[t & 1];
        float4* __restrict__       xn = buf[(t + 1) & 1];

        // prefetch x_{t+1}; latency hidden under the dot phase
        const bool pf = (t + 1 < T_) && (tid < IN4);
        if (pf) xreg = xg[(t + 1) * IN4 + tid];

        // ---- dot: each 16B broadcast read feeds 16 FMAs (4 gates x 4 elems) ----
        float accA[4] = {0.f, 0.f, 0.f, 0.f};
        float accB[4] = {0.f, 0.f, 0.f, 0.f};
#pragma unroll
        for (int j = 0; j < CH; ++j) {
            const int ci = 4 * j + q;
            if (ci < KW4) {          // compile-time true except last j on KW4%4!=0 layers
                const float4 v = xb[ci];
#pragma unroll
                for (int gi = 0; gi < 4; ++gi) {
                    accA[gi] = fmaf(w[gi][j].x, v.x, fmaf(w[gi][j].y, v.y, accA[gi]));
                    accB[gi] = fmaf(w[gi][j].z, v.z, fmaf(w[gi][j].w, v.w, accB[gi]));
                }
            }
        }

        // stage x_{t+1} into the other buffer (nobody reads it this step)
        if (pf) xn[tid] = xreg;

        // ---- quad reduce (VALU DPP) + activations; identical on all 4 lanes ----
        const float si = quad_allsum(accA[0] + accB[0]) + bias[0];
        const float sf = quad_allsum(accA[1] + accB[1]) + bias[1];
        const float sg = quad_allsum(accA[2] + accB[2]) + bias[2];
        const float so = quad_allsum(accA[3] + accB[3]) + bias[3];

        const float iv = fast_sigmoid(si);
        const float fv = fast_sigmoid(sf);
        const float gv = fast_tanh(sg);
        const float ov = fast_sigmoid(so);
        c_st = fv * c_st + iv * gv;
        const float hv = ov * fast_tanh(c_st);

        if (q == 0) {
            reinterpret_cast<float*>(xn + IN4)[h] = hv;  // next step's h
            outb[t * H + h] = hv;
        }

        // One barrier per step. Only drain LDS (ds_write of h / x-stage); the global
        // out-store is allowed to retire across steps (no vmcnt(0) drain).
        asm volatile("s_waitcnt lgkmcnt(0)\n\ts_barrier" ::: "memory");
    }
}

extern "C" void kernel_launch(void* const* d_in, const int* in_sizes, int n_in,
                              void* d_out, int out_size, void* d_ws, size_t ws_size,
                              hipStream_t stream) {
    const float* x = (const float*)d_in[0];
    const float* e1_Wih = (const float*)d_in[1];
    const float* e1_Whh = (const float*)d_in[2];
    const float* e1_bih = (const float*)d_in[3];
    const float* e1_bhh = (const float*)d_in[4];
    const float* e2_Wih = (const float*)d_in[5];
    const float* e2_Whh = (const float*)d_in[6];
    const float* e2_bih = (const float*)d_in[7];
    const float* e2_bhh = (const float*)d_in[8];
    const float* d1_Wih = (const float*)d_in[9];
    const float* d1_Whh = (const float*)d_in[10];
    const float* d1_bih = (const float*)d_in[11];
    const float* d1_bhh = (const float*)d_in[12];
    const float* d2_Wih = (const float*)d_in[13];
    const float* d2_Whh = (const float*)d_in[14];
    const float* d2_bih = (const float*)d_in[15];
    const float* d2_bhh = (const float*)d_in[16];

    float* outp = (float*)d_out;

    // Scratch layout: ws0 = e2 out [512,512,32] (32 MB), ws1 = d1 out [512,512,64] (64 MB).
    // e1 out (64 MB) borrows d_out (75.5 MB) as scratch; d2 overwrites d_out with the
    // final [512,512,72] output (reads ws1, no overlap).
    float* ws0 = (float*)d_ws;
    float* ws1 = (float*)((char*)d_ws + (size_t)B_ * T_ * 32 * sizeof(float));

    // Layer e1: 72 -> 64  (256 threads = 64 quads)
    lstm_quad_kernel<72, 64><<<B_, 256, 0, stream>>>(
        x, e1_Wih, e1_Whh, e1_bih, e1_bhh, outp);
    // Layer e2: 64 -> 32  (128 threads = 32 quads)
    lstm_quad_kernel<64, 32><<<B_, 128, 0, stream>>>(
        outp, e2_Wih, e2_Whh, e2_bih, e2_bhh, ws0);
    // Layer d1: 32 -> 64
    lstm_quad_kernel<32, 64><<<B_, 256, 0, stream>>>(
        ws0, d1_Wih, d1_Whh, d1_bih, d1_bhh, ws1);
    // Layer d2: 64 -> 72  (288 threads = 72 quads)
    lstm_quad_kernel<64, 72><<<B_, 288, 0, stream>>>(
        ws1, d2_Wih, d2_Whh, d2_bih, d2_bhh, outp);
}